// Round 6
// baseline (2621.723 us; speedup 1.0000x reference)
//
#include <hip/hip_runtime.h>

#define T_ 300
#define C_ 128
#define HB 131072  // byte offset of h double-buffer in k_lstm LDS

typedef _Float16 f16;
typedef _Float16 f16x8 __attribute__((ext_vector_type(8)));
typedef _Float16 f16x4 __attribute__((ext_vector_type(4)));
typedef float f32x4 __attribute__((ext_vector_type(4)));

#define MFMA16(a, b, c) __builtin_amdgcn_mfma_f32_16x16x32_f16((a), (b), (c), 0, 0, 0)

__device__ __forceinline__ float sigm(float x) {
    return __fdividef(1.f, 1.f + __expf(-x));
}
// tanh(x) = 1 - 2/(1 + e^{2x})
__device__ __forceinline__ float tanhx(float x) {
    float e = __expf(2.f * x);
    return __builtin_fmaf(-2.f, __frcp_rn(1.f + e), 1.f);
}

// ---------------- K0: weight conversion / pre-swizzle ----------------
__global__ void k_prep(const float* __restrict__ Wih, const float* __restrict__ Whh,
                       const float* __restrict__ bih, const float* __restrict__ bhh,
                       f16* __restrict__ wlds, f16* __restrict__ whhswz,
                       f16* __restrict__ wihswz, float* __restrict__ bsum)
{
    int i = blockIdx.x * 256 + threadIdx.x;
    if (i < 8192) {
        // W_hh k<64 portion, linear [col][64] (staged to LDS by k_lstm)
        int col = i >> 3, k0 = (i & 7) * 8;
#pragma unroll
        for (int j = 0; j < 8; j++) wlds[col * 64 + k0 + j] = (f16)Whh[col * 256 + k0 + j];
    } else if (i < 32768) {
        // W_hh kf2..7 pre-swizzled per (wave, ntile, kfi, lane)
        int q = i - 8192; int l = q & 63; q >>= 6;
        int kfi = q % 6; q /= 6; int nt = q & 7; int w = q >> 3;
        int col = 256 * (nt >> 1) + 32 * w + 16 * (nt & 1) + (l & 15);
        int k = (kfi + 2) * 32 + 8 * (l >> 4);
        f16* dst = whhswz + (((size_t)(w * 8 + nt) * 6 + kfi) * 64 + l) * 8;
#pragma unroll
        for (int j = 0; j < 8; j++) dst[j] = (f16)Whh[col * 256 + k + j];
    } else if (i < 49152) {
        // W_ih kf0..3 pre-swizzled
        int q = i - 32768; int l = q & 63; q >>= 6;
        int kfi = q & 3; q >>= 2; int nt = q & 7; int w = q >> 3;
        int col = 256 * (nt >> 1) + 32 * w + 16 * (nt & 1) + (l & 15);
        int k = kfi * 32 + 8 * (l >> 4);
        f16* dst = wihswz + (((size_t)(w * 8 + nt) * 4 + kfi) * 64 + l) * 8;
#pragma unroll
        for (int j = 0; j < 8; j++) dst[j] = (f16)Wih[col * 128 + k + j];
    } else if (i < 50176) {
        int j = i - 49152;
        bsum[j] = bih[j] + bhh[j];
    }
}

// ---------------- K1: x_proj precompute (fully parallel, all CUs) ----------------
// Produces xp (WITH bias folded in) in the exact per-lane fragment layout k_lstm
// consumes: value[r] = (d[seq=sg*16+4*quad+r, t] @ W_ih^T + bsum)[col(nt,c16)]
__global__ __launch_bounds__(512)
void k_xproj(const float* __restrict__ x, const f16* __restrict__ wihswz,
             const float* __restrict__ bsum, f16* __restrict__ xp,
             int cs, int ce, int CHT)
{
    __shared__ __align__(16) char sd[8192];  // d staging, double-buffered 2 x 4KB
    const int tid = threadIdx.x, lane = tid & 63, w = tid >> 6;
    const int sg = blockIdx.x & 15, tb = blockIdx.x >> 4;
    const int c16 = lane & 15, quad = lane >> 4;
    int ss = cs + tb * 8;
    int sse = ss + 8; if (sse > ce) sse = ce;

    f16x8 wreg[32];
#pragma unroll
    for (int kfi = 0; kfi < 4; kfi++)
#pragma unroll
        for (int nt = 0; nt < 8; nt++)
            wreg[kfi * 8 + nt] = *(const f16x8*)(wihswz + (((size_t)(w * 8 + nt) * 4 + kfi) * 64 + lane) * 8);
    // Pin the weight tile into AGPRs: frees arch VGPRs, blocks rematerialization.
#pragma unroll
    for (int i = 0; i < 32; i++) asm volatile("" : "+a"(wreg[i]));

    float bs[8];
#pragma unroll
    for (int nt = 0; nt < 8; nt++)
        bs[nt] = bsum[256 * (nt >> 1) + 32 * w + 16 * (nt & 1) + c16];

    for (int s = ss; s < sse; s++) {
        int pb = (s & 1) * 4096;
        {
            int seq = tid >> 5, cb = (tid & 31) * 4;
            const float* xr = x + ((size_t)(sg * 16 + seq) * T_ + s) * C_ + cb;
            float4 x0 = *(const float4*)xr;
            float4 x1 = *(const float4*)(xr + C_);
            f16x4 d4 = {(f16)(x1.x - x0.x), (f16)(x1.y - x0.y),
                        (f16)(x1.z - x0.z), (f16)(x1.w - x0.w)};
            *(f16x4*)(sd + pb + ((seq * 256 + cb * 2) ^ ((seq & 7) << 4))) = d4;
        }
        __syncthreads();
        f32x4 a[8];
#pragma unroll
        for (int nt = 0; nt < 8; nt++) a[nt] = (f32x4){0.f, 0.f, 0.f, 0.f};
#pragma unroll
        for (int kf = 0; kf < 4; kf++) {
            f16x8 af = *(const f16x8*)(sd + pb + ((c16 * 256 + (kf * 32 + 8 * quad) * 2) ^ ((c16 & 7) << 4)));
#pragma unroll
            for (int nt = 0; nt < 8; nt++) a[nt] = MFMA16(af, wreg[kf * 8 + nt], a[nt]);
        }
        f16* ob = xp + ((((size_t)sg * CHT + (s - cs)) * 8 + w) * 8) * 256 + lane * 4;
#pragma unroll
        for (int nt = 0; nt < 8; nt++) {
            f16x4 o = {(f16)(a[nt].x + bs[nt]), (f16)(a[nt].y + bs[nt]),
                       (f16)(a[nt].z + bs[nt]), (f16)(a[nt].w + bs[nt])};
            *(f16x4*)(ob + nt * 256) = o;
        }
    }
}

// ---------------- K2: recurrence (32 WGs x 512 thr; 1 WG per 16 seqs per window) ----------------
// LDS: [0,131072)        W_hh k<64, [1024 cols][64 k] f16, XOR-swizzled
//      [131072,147456)   h double buffer, 2 x [16 seq][256 j] f16, XOR-swizzled
// Budget: 512-thread WG + 144KB LDS => 2 waves/SIMD => 256 UNIFIED regs/wave.
// wreg (128 regs, MFMA-B-only) is pinned to AGPRs via "+a" empty asm; the
// arch-VGPR live set (acc 32 + sf 16 + xc 8 + state 24 + temps) fits in 128.
__global__ __launch_bounds__(512)
__attribute__((amdgpu_waves_per_eu(2, 2)))
void k_lstm(const f16* __restrict__ wlds_src, const f16* __restrict__ whhswz,
            const float* __restrict__ bsum, const f16* __restrict__ xp,
            float* __restrict__ feat, char* __restrict__ hstate,
            float* __restrict__ cstate, float* __restrict__ poolstate,
            int cs, int ce, int CHT)
{
    __shared__ __align__(16) char lds[147456];
    const int tid = threadIdx.x, lane = tid & 63, w = tid >> 6;
    const int wg = blockIdx.x, win = wg >> 4, sg = wg & 15;
    const int c16 = lane & 15, quad = lane >> 4;
    const int a1 = win ? 299 : 154;   // active (nonzero-input) end
    const int t0 = win ? 145 : 0;     // first step
    int s0 = cs > t0 ? cs : t0;
    const int se = ce < 299 ? ce : 299;
    if (s0 >= se) return;
    const bool init = (s0 == t0);

    // stage W k<64 (swizzled)
#pragma unroll
    for (int cc = 0; cc < 2; cc++) {
        int col = tid * 2 + cc;
#pragma unroll
        for (int kb = 0; kb < 8; kb++) {
            f16x8 v = *(const f16x8*)(wlds_src + col * 64 + kb * 8);
            int byte = (col * 128 + kb * 16) ^ ((col & 7) << 4);
            *(f16x8*)(lds + byte) = v;
        }
    }
    // restore / zero the h read-slot for step s0 (parity (s0-1)&1)
    {
        char* slot = lds + HB + (((s0 - 1) & 1) * 8192);
        if (init) {
            f16x8 z = {0, 0, 0, 0, 0, 0, 0, 0};
            *(f16x8*)(slot + tid * 16) = z;
        } else {
            *(f16x8*)(slot + tid * 16) = *(const f16x8*)(hstate + (size_t)wg * 8192 + tid * 16);
        }
    }

    float bs[8];
#pragma unroll
    for (int nt = 0; nt < 8; nt++)
        bs[nt] = bsum[256 * (nt >> 1) + 32 * w + 16 * (nt & 1) + c16];

    f16x8 wreg[32];  // W_hh k 64..192, resident in AGPRs for the whole kernel
#pragma unroll
    for (int kfi = 0; kfi < 4; kfi++)
#pragma unroll
        for (int nt = 0; nt < 8; nt++)
            wreg[kfi * 8 + nt] = *(const f16x8*)(whhswz + (((size_t)(w * 8 + nt) * 6 + kfi) * 64 + lane) * 8);
    // Pin to AGPRs: opaque asm output can't be rematerialized, and the 128
    // regs move out of the contested arch-VGPR half of the unified file.
#pragma unroll
    for (int i = 0; i < 32; i++) asm volatile("" : "+a"(wreg[i]));

    float cst[8], pool[8];
    if (init) {
#pragma unroll
        for (int i = 0; i < 8; i++) { cst[i] = 0.f; pool[i] = 0.f; }
    } else {
        const float* cp = cstate + ((size_t)wg * 512 + tid) * 8;
        const float* pp = poolstate + ((size_t)wg * 512 + tid) * 8;
#pragma unroll
        for (int i = 0; i < 8; i++) { cst[i] = cp[i]; pool[i] = pp[i]; }
    }

    __syncthreads();

    // x_proj fragment pointer (advances 64*256 f16 = 32KB per step)
    const f16* xptr = xp + (((size_t)sg * CHT + (s0 - cs)) * 64) * 256 + (size_t)w * 8 * 256 + lane * 4;
    f16x4 xc[8];
    if (s0 < a1) {
#pragma unroll
        for (int nt = 0; nt < 8; nt++) xc[nt] = *(const f16x4*)(xptr + nt * 256);
    }

    for (int t = s0; t < se; ++t) {
        int tdep = 0;
        asm volatile("" : "+v"(tdep));   // keep streamed loads inside the loop
        const f16* wsp = whhswz + tdep;
        // issue streamed weights kfi=4 (k 192..224) — consumed one MFMA section later
        f16x8 sf[8];
#pragma unroll
        for (int nt = 0; nt < 8; nt++)
            sf[nt] = *(const f16x8*)(wsp + (((size_t)(w * 8 + nt) * 6 + 4) * 64 + lane) * 8);
        // acc init (bias already folded into xp)
        f32x4 acc[8];
        if (t < a1) {
#pragma unroll
            for (int nt = 0; nt < 8; nt++)
                acc[nt] = (f32x4){(float)xc[nt].x, (float)xc[nt].y,
                                  (float)xc[nt].z, (float)xc[nt].w};
        } else {
#pragma unroll
            for (int nt = 0; nt < 8; nt++) acc[nt] = (f32x4){bs[nt], bs[nt], bs[nt], bs[nt]};
        }
        // prefetch next step's x_proj into xc (WAR after acc init)
        xptr += 16384;
        if ((t + 1 < se) && (t + 1 < a1)) {
#pragma unroll
            for (int nt = 0; nt < 8; nt++) xc[nt] = *(const f16x4*)(xptr + nt * 256);
        }
        const int rb = HB + (((t + 1) & 1)) * 8192;
        const int wb = HB + ((t & 1)) * 8192;
        const int abase = c16 * 512;
        const int aswz = (c16 & 7) << 4;
        // k 64..192 from AGPR-resident wreg (covers sf's L2 latency)
#pragma unroll
        for (int kf = 2; kf < 6; kf++) {
            f16x8 af = *(const f16x8*)(lds + rb + ((abase + (kf * 32 + 8 * quad) * 2) ^ aswz));
#pragma unroll
            for (int nt = 0; nt < 8; nt++) acc[nt] = MFMA16(af, wreg[(kf - 2) * 8 + nt], acc[nt]);
        }
        // consume sf (kf=6)
        {
            f16x8 af = *(const f16x8*)(lds + rb + ((abase + (6 * 32 + 8 * quad) * 2) ^ aswz));
#pragma unroll
            for (int nt = 0; nt < 8; nt++) acc[nt] = MFMA16(af, sf[nt], acc[nt]);
        }
        // issue streamed weights kfi=5 (k 224..256) into the SAME buffer
#pragma unroll
        for (int nt = 0; nt < 8; nt++)
            sf[nt] = *(const f16x8*)(wsp + (((size_t)(w * 8 + nt) * 6 + 5) * 64 + lane) * 8);
        // k 0..64 from LDS W image (covers sf's L2 latency)
#pragma unroll
        for (int kf = 0; kf < 2; kf++) {
            f16x8 af = *(const f16x8*)(lds + rb + ((abase + (kf * 32 + 8 * quad) * 2) ^ aswz));
#pragma unroll
            for (int nt = 0; nt < 8; nt++) {
                int col = 256 * (nt >> 1) + 32 * w + 16 * (nt & 1) + c16;
                f16x8 bf = *(const f16x8*)(lds + ((col * 128 + (kf * 32 + 8 * quad) * 2) ^ ((col & 7) << 4)));
                acc[nt] = MFMA16(af, bf, acc[nt]);
            }
        }
        // consume sf (kf=7)
        {
            f16x8 af = *(const f16x8*)(lds + rb + ((abase + (7 * 32 + 8 * quad) * 2) ^ aswz));
#pragma unroll
            for (int nt = 0; nt < 8; nt++) acc[nt] = MFMA16(af, sf[nt], acc[nt]);
        }
        // gate math: acc layout D[m=4*quad+r][col]; nt = gate*2 + sub
#pragma unroll
        for (int sub = 0; sub < 2; sub++) {
#pragma unroll
            for (int r = 0; r < 4; r++) {
                float gi = acc[0 + sub][r], gf = acc[2 + sub][r];
                float gg = acc[4 + sub][r], go = acc[6 + sub][r];
                int ci = sub * 4 + r;
                float c_ = sigm(gf) * cst[ci] + sigm(gi) * tanhx(gg);
                cst[ci] = c_;
                float h_ = sigm(go) * tanhx(c_);
                pool[ci] += h_;
                int m = 4 * quad + r;
                int j = 32 * w + 16 * sub + c16;
                int byte = wb + ((m * 512 + j * 2) ^ ((m & 7) << 4));
                *(f16*)(lds + byte) = (f16)h_;
            }
        }
        __syncthreads();
    }

    if (se < 299) {
        // save state (h slot stable after final barrier)
        const char* slot = lds + HB + (((se - 1) & 1) * 8192);
        *(f16x8*)(hstate + (size_t)wg * 8192 + tid * 16) = *(const f16x8*)(slot + tid * 16);
        float* cp = cstate + ((size_t)wg * 512 + tid) * 8;
        float* pp = poolstate + ((size_t)wg * 512 + tid) * 8;
#pragma unroll
        for (int i = 0; i < 8; i++) { cp[i] = cst[i]; pp[i] = pool[i]; }
    } else {
        // pooled hidden -> feat (window-major concat)
#pragma unroll
        for (int sub = 0; sub < 2; sub++)
#pragma unroll
            for (int r = 0; r < 4; r++) {
                int m = 4 * quad + r;
                int j = 32 * w + 16 * sub + c16;
                feat[(size_t)(sg * 16 + m) * 512 + win * 256 + j] = pool[sub * 4 + r];
            }
    }
}

// ---------------- K3: final FC ----------------
__global__ void k_fc(const float* __restrict__ feat, const float* __restrict__ Wfc,
                     const float* __restrict__ bfc, float* __restrict__ out)
{
    int b = blockIdx.x, c = threadIdx.x;
    if (c < 60) {
        const float4* fr = (const float4*)(feat + (size_t)b * 512);
        const float4* wr = (const float4*)(Wfc + (size_t)c * 512);
        float s = bfc[c];
        for (int k = 0; k < 128; k++) {
            float4 f = fr[k], ww = wr[k];
            s += f.x * ww.x + f.y * ww.y + f.z * ww.z + f.w * ww.w;
        }
        out[b * 60 + c] = s;
    }
}

extern "C" void kernel_launch(void* const* d_in, const int* in_sizes, int n_in,
                              void* d_out, int out_size, void* d_ws, size_t ws_size,
                              hipStream_t stream)
{
    const float* x   = (const float*)d_in[0];
    const float* Wih = (const float*)d_in[1];
    const float* Whh = (const float*)d_in[2];
    const float* bih = (const float*)d_in[3];
    const float* bhh = (const float*)d_in[4];
    const float* Wfc = (const float*)d_in[5];
    const float* bfc = (const float*)d_in[6];
    float* out = (float*)d_out;

    char* p = (char*)d_ws;
    f16* wlds    = (f16*)p;   p += 131072;            // W_hh k<64 (LDS image)
    f16* whhswz  = (f16*)p;   p += 393216;            // W_hh k 64..256 pre-swizzled
    f16* wihswz  = (f16*)p;   p += 262144;            // W_ih pre-swizzled
    float* bsum  = (float*)p; p += 4096;
    float* feat  = (float*)p; p += 524288;            // (256, 512) pooled features
    char* hstate = p;         p += 262144;            // 32 WG x 8KB raw h LDS image
    float* cstate = (float*)p;    p += 524288;
    float* poolstate = (float*)p; p += 524288;
    f16* xp = (f16*)p;
    size_t fixed = (size_t)(p - (char*)d_ws);

    long long avail = (long long)ws_size - (long long)fixed;
    int CHT = (int)(avail / 524288);                  // 512KB of xp per step
    if (CHT < 1) CHT = 1;
    if (CHT > 299) CHT = 299;

    k_prep<<<196, 256, 0, stream>>>(Wih, Whh, bih, bhh, wlds, whhswz, wihswz, bsum);
    for (int cs = 0; cs < 299; cs += CHT) {
        int ce = cs + CHT; if (ce > 299) ce = 299;
        int nb = (ce - cs + 7) / 8;
        k_xproj<<<16 * nb, 512, 0, stream>>>(x, wihswz, bsum, xp, cs, ce, CHT);
        k_lstm<<<32, 512, 0, stream>>>(wlds, whhswz, bsum, xp, feat,
                                       hstate, cstate, poolstate, cs, ce, CHT);
    }
    k_fc<<<256, 64, 0, stream>>>(feat, Wfc, bfc, out);
}

// Round 7
// 2252.102 us; speedup vs baseline: 1.1641x; 1.1641x over previous
//
#include <hip/hip_runtime.h>

#define T_ 300
#define C_ 128
#define HB 131072  // byte offset of h double-buffer in k_lstm LDS

typedef _Float16 f16;
typedef _Float16 f16x8 __attribute__((ext_vector_type(8)));
typedef _Float16 f16x4 __attribute__((ext_vector_type(4)));
typedef _Float16 f16x2 __attribute__((ext_vector_type(2)));
typedef float f32x4 __attribute__((ext_vector_type(4)));

#define MFMA16(a, b, c) __builtin_amdgcn_mfma_f32_16x16x32_f16((a), (b), (c), 0, 0, 0)

__device__ __forceinline__ float sigm(float x) {
    return __fdividef(1.f, 1.f + __expf(-x));
}
// tanh(x) = 1 - 2/(1 + e^{2x})
__device__ __forceinline__ float tanhx(float x) {
    float e = __expf(2.f * x);
    return __builtin_fmaf(-2.f, __frcp_rn(1.f + e), 1.f);
}

// ---------------- K0: weight conversion / pre-swizzle ----------------
// New fragment layouts are per (wave w16=0..15, gate g=0..3): col = g*256 + 16*w16 + (l&15)
__global__ void k_prep(const float* __restrict__ Wih, const float* __restrict__ Whh,
                       const float* __restrict__ bih, const float* __restrict__ bhh,
                       f16* __restrict__ wlds, f16* __restrict__ whhswz,
                       f16* __restrict__ wihswz, float* __restrict__ bsum)
{
    int i = blockIdx.x * 256 + threadIdx.x;
    if (i < 8192) {
        // W_hh k<64 portion, linear [col][64] (staged to LDS by k_lstm)
        int col = i >> 3, k0 = (i & 7) * 8;
#pragma unroll
        for (int j = 0; j < 8; j++) wlds[col * 64 + k0 + j] = (f16)Whh[col * 256 + k0 + j];
    } else if (i < 32768) {
        // W_hh k64..256 pre-swizzled per (w16, g, kfi 0..5, lane)
        int q = i - 8192; int l = q & 63; q >>= 6;   // q 0..383
        int kfi = q % 6; q /= 6;                     // q 0..63
        int g = q & 3, w16 = q >> 2;
        int col = g * 256 + 16 * w16 + (l & 15);
        int k = 64 + kfi * 32 + 8 * (l >> 4);
        f16* dst = whhswz + (((size_t)(w16 * 4 + g) * 6 + kfi) * 64 + l) * 8;
#pragma unroll
        for (int j = 0; j < 8; j++) dst[j] = (f16)Whh[col * 256 + k + j];
    } else if (i < 49152) {
        // W_ih k0..128 pre-swizzled per (w16, g, kfi 0..3, lane)
        int q = i - 32768; int l = q & 63; q >>= 6;  // q 0..255
        int kfi = q & 3; q >>= 2;                    // q 0..63
        int g = q & 3, w16 = q >> 2;
        int col = g * 256 + 16 * w16 + (l & 15);
        int k = kfi * 32 + 8 * (l >> 4);
        f16* dst = wihswz + (((size_t)(w16 * 4 + g) * 4 + kfi) * 64 + l) * 8;
#pragma unroll
        for (int j = 0; j < 8; j++) dst[j] = (f16)Wih[col * 128 + k + j];
    } else if (i < 50176) {
        int j = i - 49152;
        bsum[j] = bih[j] + bhh[j];
    }
}

// ---------------- K1: x_proj precompute (fully parallel) ----------------
// 1024 thr / 16 waves; wave w: j-block 16w, gates g=0..3. Low register pressure
// by design (wreg 16 frags = 64 regs, acc 16). Bias folded into xp.
__global__ __launch_bounds__(1024)
__attribute__((amdgpu_waves_per_eu(4, 4)))
void k_xproj(const float* __restrict__ x, const f16* __restrict__ wihswz,
             const float* __restrict__ bsum, f16* __restrict__ xp,
             int cs, int ce, int CHT)
{
    __shared__ __align__(16) char sd[8192];  // d staging, double-buffered 2 x 4KB
    const int tid = threadIdx.x, lane = tid & 63, w = tid >> 6;
    const int sg = blockIdx.x & 15, tb = blockIdx.x >> 4;
    const int c16 = lane & 15, quad = lane >> 4;
    int ss = cs + tb * 8;
    int sse = ss + 8; if (sse > ce) sse = ce;

    f16x8 wreg[16];
#pragma unroll
    for (int g = 0; g < 4; g++)
#pragma unroll
        for (int kfi = 0; kfi < 4; kfi++)
            wreg[g * 4 + kfi] = *(const f16x8*)(wihswz + (((size_t)(w * 4 + g) * 4 + kfi) * 64 + lane) * 8);

    float bs[4];
#pragma unroll
    for (int g = 0; g < 4; g++) bs[g] = bsum[g * 256 + 16 * w + c16];

    for (int s = ss; s < sse; s++) {
        int pb = (s & 1) * 4096;
        {
            int seq = tid >> 6, cb = (tid & 63) * 2;  // 64 threads/seq, 2 cols each
            const float* xr = x + ((size_t)(sg * 16 + seq) * T_ + s) * C_ + cb;
            float a0 = xr[0], a1 = xr[1], b0 = xr[C_], b1 = xr[C_ + 1];
            f16x2 d2 = {(f16)(b0 - a0), (f16)(b1 - a1)};
            *(f16x2*)(sd + pb + ((seq * 256 + cb * 2) ^ ((seq & 7) << 4))) = d2;
        }
        __syncthreads();
        f32x4 a[4];
#pragma unroll
        for (int g = 0; g < 4; g++) a[g] = (f32x4){0.f, 0.f, 0.f, 0.f};
#pragma unroll
        for (int kf = 0; kf < 4; kf++) {
            f16x8 af = *(const f16x8*)(sd + pb + ((c16 * 256 + (kf * 32 + 8 * quad) * 2) ^ ((c16 & 7) << 4)));
#pragma unroll
            for (int g = 0; g < 4; g++) a[g] = MFMA16(af, wreg[g * 4 + kf], a[g]);
        }
        f16* ob = xp + (((size_t)sg * CHT + (s - cs)) * 16 + w) * 1024 + lane * 4;
#pragma unroll
        for (int g = 0; g < 4; g++) {
            f16x4 o = {(f16)(a[g].x + bs[g]), (f16)(a[g].y + bs[g]),
                       (f16)(a[g].z + bs[g]), (f16)(a[g].w + bs[g])};
            *(f16x4*)(ob + g * 256) = o;
        }
    }
}

// ---------------- K2: recurrence (32 WGs x 1024 thr; 1 WG per 16 seqs per window) ----------------
// 16 waves, 4/SIMD -> 128-VGPR budget. Per-wave live set DESIGNED for 128:
// wave w owns j-block 16w and all 4 gates: wreg 8 frags (k64..128) = 32 regs,
// sf 4 frags (stream k128..256 in 4 groups) = 16, acc[4] = 16, xc 8, state 12.
// LDS: [0,131072) W_hh k<64 image; [131072,147456) h double buffer (swizzled).
__global__ __launch_bounds__(1024)
__attribute__((amdgpu_waves_per_eu(4, 4)))
void k_lstm(const f16* __restrict__ wlds_src, const f16* __restrict__ whhswz,
            const float* __restrict__ bsum, const f16* __restrict__ xp,
            float* __restrict__ feat, char* __restrict__ hstate,
            float* __restrict__ cstate, float* __restrict__ poolstate,
            int cs, int ce, int CHT)
{
    __shared__ __align__(16) char lds[147456];
    const int tid = threadIdx.x, lane = tid & 63, w = tid >> 6;  // w 0..15
    const int wg = blockIdx.x, win = wg >> 4, sg = wg & 15;
    const int c16 = lane & 15, quad = lane >> 4;
    const int a1 = win ? 299 : 154;   // active (nonzero-input) end
    const int t0 = win ? 145 : 0;     // first step
    int s0 = cs > t0 ? cs : t0;
    const int se = ce < 299 ? ce : 299;
    if (s0 >= se) return;
    const bool init = (s0 == t0);

    // stage W k<64 image (swizzled): 1024 threads x 1 col x 128B
    {
        int col = tid;
#pragma unroll
        for (int kb = 0; kb < 8; kb++) {
            f16x8 v = *(const f16x8*)(wlds_src + col * 64 + kb * 8);
            int byte = (col * 128 + kb * 16) ^ ((col & 7) << 4);
            *(f16x8*)(lds + byte) = v;
        }
    }
    // restore / zero the h read-slot for step s0 (parity (s0-1)&1), 8B/thread
    {
        char* slot = lds + HB + (((s0 - 1) & 1) * 8192);
        if (init) {
            f16x4 z = {0, 0, 0, 0};
            *(f16x4*)(slot + tid * 8) = z;
        } else {
            *(f16x4*)(slot + tid * 8) = *(const f16x4*)(hstate + (size_t)wg * 8192 + tid * 8);
        }
    }

    float bs[4];
#pragma unroll
    for (int g = 0; g < 4; g++) bs[g] = bsum[g * 256 + 16 * w + c16];

    f16x8 wreg[8];  // W_hh k64..128 (kfi 0,1), resident
#pragma unroll
    for (int kfi = 0; kfi < 2; kfi++)
#pragma unroll
        for (int g = 0; g < 4; g++)
            wreg[kfi * 4 + g] = *(const f16x8*)(whhswz + (((size_t)(w * 4 + g) * 6 + kfi) * 64 + lane) * 8);

    float cst[4], pool[4];
    if (init) {
#pragma unroll
        for (int i = 0; i < 4; i++) { cst[i] = 0.f; pool[i] = 0.f; }
    } else {
        const float* cp = cstate + ((size_t)wg * 1024 + tid) * 4;
        const float* pp = poolstate + ((size_t)wg * 1024 + tid) * 4;
#pragma unroll
        for (int i = 0; i < 4; i++) { cst[i] = cp[i]; pool[i] = pp[i]; }
    }

    __syncthreads();

    // x_proj fragment pointer (advances 16 waves * 1024 f16 = 32KB per step)
    const f16* xptr = xp + (((size_t)sg * CHT + (s0 - cs)) * 16 + w) * 1024 + lane * 4;
    f16x4 xc[4];
    if (s0 < a1) {
#pragma unroll
        for (int g = 0; g < 4; g++) xc[g] = *(const f16x4*)(xptr + g * 256);
    }

    const int aswz = (c16 & 7) << 4;
    for (int t = s0; t < se; ++t) {
        int tdep = 0;
        asm volatile("" : "+v"(tdep));   // keep streamed loads inside the loop
        const f16* wsp = whhswz + tdep;
        f16x8 sf[4];
        // issue stream kfi=2 (k128..160)
#pragma unroll
        for (int g = 0; g < 4; g++)
            sf[g] = *(const f16x8*)(wsp + (((size_t)(w * 4 + g) * 6 + 2) * 64 + lane) * 8);
        // acc init (bias folded into xp)
        f32x4 acc[4];
        if (t < a1) {
#pragma unroll
            for (int g = 0; g < 4; g++)
                acc[g] = (f32x4){(float)xc[g].x, (float)xc[g].y, (float)xc[g].z, (float)xc[g].w};
        } else {
#pragma unroll
            for (int g = 0; g < 4; g++) acc[g] = (f32x4){bs[g], bs[g], bs[g], bs[g]};
        }
        // prefetch next step's x_proj (WAR after acc init)
        xptr += 16384;
        if ((t + 1 < se) && (t + 1 < a1)) {
#pragma unroll
            for (int g = 0; g < 4; g++) xc[g] = *(const f16x4*)(xptr + g * 256);
        }
        const int rb = HB + (((t + 1) & 1)) * 8192;
        const int wb = HB + ((t & 1)) * 8192;
        const int abase = c16 * 512;
        // kf2,kf3 from wreg (shadow for kfi2 stream)
#pragma unroll
        for (int k = 0; k < 2; k++) {
            f16x8 af = *(const f16x8*)(lds + rb + ((abase + ((2 + k) * 32 + 8 * quad) * 2) ^ aswz));
#pragma unroll
            for (int g = 0; g < 4; g++) acc[g] = MFMA16(af, wreg[k * 4 + g], acc[g]);
        }
        // consume kfi2 -> kf4; issue kfi3
        {
            f16x8 af = *(const f16x8*)(lds + rb + ((abase + (4 * 32 + 8 * quad) * 2) ^ aswz));
#pragma unroll
            for (int g = 0; g < 4; g++) acc[g] = MFMA16(af, sf[g], acc[g]);
#pragma unroll
            for (int g = 0; g < 4; g++)
                sf[g] = *(const f16x8*)(wsp + (((size_t)(w * 4 + g) * 6 + 3) * 64 + lane) * 8);
        }
        // kf0 from LDS image (shadow for kfi3)
        {
            f16x8 af = *(const f16x8*)(lds + rb + ((abase + (0 * 32 + 8 * quad) * 2) ^ aswz));
#pragma unroll
            for (int g = 0; g < 4; g++) {
                int col = g * 256 + 16 * w + c16;
                f16x8 bf = *(const f16x8*)(lds + ((col * 128 + (0 * 32 + 8 * quad) * 2) ^ aswz));
                acc[g] = MFMA16(af, bf, acc[g]);
            }
        }
        // consume kfi3 -> kf5; issue kfi4
        {
            f16x8 af = *(const f16x8*)(lds + rb + ((abase + (5 * 32 + 8 * quad) * 2) ^ aswz));
#pragma unroll
            for (int g = 0; g < 4; g++) acc[g] = MFMA16(af, sf[g], acc[g]);
#pragma unroll
            for (int g = 0; g < 4; g++)
                sf[g] = *(const f16x8*)(wsp + (((size_t)(w * 4 + g) * 6 + 4) * 64 + lane) * 8);
        }
        // kf1 from LDS image (shadow for kfi4)
        {
            f16x8 af = *(const f16x8*)(lds + rb + ((abase + (1 * 32 + 8 * quad) * 2) ^ aswz));
#pragma unroll
            for (int g = 0; g < 4; g++) {
                int col = g * 256 + 16 * w + c16;
                f16x8 bf = *(const f16x8*)(lds + ((col * 128 + (1 * 32 + 8 * quad) * 2) ^ aswz));
                acc[g] = MFMA16(af, bf, acc[g]);
            }
        }
        // consume kfi4 -> kf6; issue kfi5
        {
            f16x8 af = *(const f16x8*)(lds + rb + ((abase + (6 * 32 + 8 * quad) * 2) ^ aswz));
#pragma unroll
            for (int g = 0; g < 4; g++) acc[g] = MFMA16(af, sf[g], acc[g]);
#pragma unroll
            for (int g = 0; g < 4; g++)
                sf[g] = *(const f16x8*)(wsp + (((size_t)(w * 4 + g) * 6 + 5) * 64 + lane) * 8);
        }
        // consume kfi5 -> kf7
        {
            f16x8 af = *(const f16x8*)(lds + rb + ((abase + (7 * 32 + 8 * quad) * 2) ^ aswz));
#pragma unroll
            for (int g = 0; g < 4; g++) acc[g] = MFMA16(af, sf[g], acc[g]);
        }
        // gate math: acc[g][r] = gate g, seq m=4*quad+r, j = 16w + c16
#pragma unroll
        for (int r = 0; r < 4; r++) {
            float gi = acc[0][r], gf = acc[1][r], gg = acc[2][r], go = acc[3][r];
            float c_ = sigm(gf) * cst[r] + sigm(gi) * tanhx(gg);
            cst[r] = c_;
            float h_ = sigm(go) * tanhx(c_);
            pool[r] += h_;
            int m = 4 * quad + r;
            int j = 16 * w + c16;
            int byte = wb + ((m * 512 + j * 2) ^ ((m & 7) << 4));
            *(f16*)(lds + byte) = (f16)h_;
        }
        __syncthreads();
    }

    if (se < 299) {
        // save state (h slot stable after final barrier)
        const char* slot = lds + HB + (((se - 1) & 1) * 8192);
        *(f16x4*)(hstate + (size_t)wg * 8192 + tid * 8) = *(const f16x4*)(slot + tid * 8);
        float* cp = cstate + ((size_t)wg * 1024 + tid) * 4;
        float* pp = poolstate + ((size_t)wg * 1024 + tid) * 4;
#pragma unroll
        for (int i = 0; i < 4; i++) { cp[i] = cst[i]; pp[i] = pool[i]; }
    } else {
        // pooled hidden -> feat (window-major concat)
#pragma unroll
        for (int r = 0; r < 4; r++) {
            int m = 4 * quad + r;
            int j = 16 * w + c16;
            feat[(size_t)(sg * 16 + m) * 512 + win * 256 + j] = pool[r];
        }
    }
}

// ---------------- K3: final FC ----------------
__global__ void k_fc(const float* __restrict__ feat, const float* __restrict__ Wfc,
                     const float* __restrict__ bfc, float* __restrict__ out)
{
    int b = blockIdx.x, c = threadIdx.x;
    if (c < 60) {
        const float4* fr = (const float4*)(feat + (size_t)b * 512);
        const float4* wr = (const float4*)(Wfc + (size_t)c * 512);
        float s = bfc[c];
        for (int k = 0; k < 128; k++) {
            float4 f = fr[k], ww = wr[k];
            s += f.x * ww.x + f.y * ww.y + f.z * ww.z + f.w * ww.w;
        }
        out[b * 60 + c] = s;
    }
}

extern "C" void kernel_launch(void* const* d_in, const int* in_sizes, int n_in,
                              void* d_out, int out_size, void* d_ws, size_t ws_size,
                              hipStream_t stream)
{
    const float* x   = (const float*)d_in[0];
    const float* Wih = (const float*)d_in[1];
    const float* Whh = (const float*)d_in[2];
    const float* bih = (const float*)d_in[3];
    const float* bhh = (const float*)d_in[4];
    const float* Wfc = (const float*)d_in[5];
    const float* bfc = (const float*)d_in[6];
    float* out = (float*)d_out;

    char* p = (char*)d_ws;
    f16* wlds    = (f16*)p;   p += 131072;            // W_hh k<64 (LDS image)
    f16* whhswz  = (f16*)p;   p += 393216;            // W_hh k64..256 pre-swizzled
    f16* wihswz  = (f16*)p;   p += 262144;            // W_ih pre-swizzled
    float* bsum  = (float*)p; p += 4096;
    float* feat  = (float*)p; p += 524288;            // (256, 512) pooled features
    char* hstate = p;         p += 262144;            // 32 WG x 8KB raw h LDS image
    float* cstate = (float*)p;    p += 524288;
    float* poolstate = (float*)p; p += 524288;
    f16* xp = (f16*)p;
    size_t fixed = (size_t)(p - (char*)d_ws);

    long long avail = (long long)ws_size - (long long)fixed;
    int CHT = (int)(avail / 524288);                  // 512KB of xp per step
    if (CHT < 1) CHT = 1;
    if (CHT > 64) CHT = 64;                           // keep xp chunk L3/L2-hot (32MB)

    k_prep<<<196, 256, 0, stream>>>(Wih, Whh, bih, bhh, wlds, whhswz, wihswz, bsum);
    for (int cs = 0; cs < 299; cs += CHT) {
        int ce = cs + CHT; if (ce > 299) ce = 299;
        int nb = (ce - cs + 7) / 8;
        k_xproj<<<16 * nb, 1024, 0, stream>>>(x, wihswz, bsum, xp, cs, ce, CHT);
        k_lstm<<<32, 1024, 0, stream>>>(wlds, whhswz, bsum, xp, feat,
                                        hstate, cstate, poolstate, cs, ce, CHT);
    }
    k_fc<<<256, 64, 0, stream>>>(feat, Wfc, bfc, out);
}

// Round 8
// 2098.762 us; speedup vs baseline: 1.2492x; 1.0731x over previous
//
#include <hip/hip_runtime.h>

#define T_ 300
#define C_ 128
#define HB 131072  // byte offset of h double-buffer in k_lstm LDS

typedef _Float16 f16;
typedef _Float16 f16x8 __attribute__((ext_vector_type(8)));
typedef _Float16 f16x4 __attribute__((ext_vector_type(4)));
typedef _Float16 f16x2 __attribute__((ext_vector_type(2)));
typedef float f32x4 __attribute__((ext_vector_type(4)));

#define MFMA16(a, b, c) __builtin_amdgcn_mfma_f32_16x16x32_f16((a), (b), (c), 0, 0, 0)

__device__ __forceinline__ float sigm(float x) {
    return __fdividef(1.f, 1.f + __expf(-x));
}
// tanh(x) = 1 - 2/(1 + e^{2x})
__device__ __forceinline__ float tanhx(float x) {
    float e = __expf(2.f * x);
    return __builtin_fmaf(-2.f, __frcp_rn(1.f + e), 1.f);
}

// ---------------- K0: weight conversion / pre-swizzle ----------------
// Fragment layouts per (wave w16=0..15, gate g=0..3): col = g*256 + 16*w16 + (l&15)
__global__ void k_prep(const float* __restrict__ Wih, const float* __restrict__ Whh,
                       const float* __restrict__ bih, const float* __restrict__ bhh,
                       f16* __restrict__ wlds, f16* __restrict__ whhswz,
                       f16* __restrict__ wihswz, float* __restrict__ bsum)
{
    int i = blockIdx.x * 256 + threadIdx.x;
    if (i < 8192) {
        // W_hh k<64 portion, linear [col][64] (staged to LDS by k_lstm)
        int col = i >> 3, k0 = (i & 7) * 8;
#pragma unroll
        for (int j = 0; j < 8; j++) wlds[col * 64 + k0 + j] = (f16)Whh[col * 256 + k0 + j];
    } else if (i < 32768) {
        // W_hh k64..256 pre-swizzled per (w16, g, kfi 0..5, lane)
        int q = i - 8192; int l = q & 63; q >>= 6;   // q 0..383
        int kfi = q % 6; q /= 6;                     // q 0..63
        int g = q & 3, w16 = q >> 2;
        int col = g * 256 + 16 * w16 + (l & 15);
        int k = 64 + kfi * 32 + 8 * (l >> 4);
        f16* dst = whhswz + (((size_t)(w16 * 4 + g) * 6 + kfi) * 64 + l) * 8;
#pragma unroll
        for (int j = 0; j < 8; j++) dst[j] = (f16)Whh[col * 256 + k + j];
    } else if (i < 49152) {
        // W_ih k0..128 pre-swizzled per (w16, g, kfi 0..3, lane)
        int q = i - 32768; int l = q & 63; q >>= 6;  // q 0..255
        int kfi = q & 3; q >>= 2;                    // q 0..63
        int g = q & 3, w16 = q >> 2;
        int col = g * 256 + 16 * w16 + (l & 15);
        int k = kfi * 32 + 8 * (l >> 4);
        f16* dst = wihswz + (((size_t)(w16 * 4 + g) * 4 + kfi) * 64 + l) * 8;
#pragma unroll
        for (int j = 0; j < 8; j++) dst[j] = (f16)Wih[col * 128 + k + j];
    } else if (i < 50176) {
        int j = i - 49152;
        bsum[j] = bih[j] + bhh[j];
    }
}

// ---------------- K1: x_proj precompute (fully parallel) ----------------
__global__ __launch_bounds__(1024)
__attribute__((amdgpu_waves_per_eu(4, 4)))
void k_xproj(const float* __restrict__ x, const f16* __restrict__ wihswz,
             const float* __restrict__ bsum, f16* __restrict__ xp,
             int cs, int ce, int CHT)
{
    __shared__ __align__(16) char sd[8192];  // d staging, double-buffered 2 x 4KB
    const int tid = threadIdx.x, lane = tid & 63, w = tid >> 6;
    const int sg = blockIdx.x & 15, tb = blockIdx.x >> 4;
    const int c16 = lane & 15, quad = lane >> 4;
    int ss = cs + tb * 8;
    int sse = ss + 8; if (sse > ce) sse = ce;

    f16x8 wreg[16];
#pragma unroll
    for (int g = 0; g < 4; g++)
#pragma unroll
        for (int kfi = 0; kfi < 4; kfi++)
            wreg[g * 4 + kfi] = *(const f16x8*)(wihswz + (((size_t)(w * 4 + g) * 4 + kfi) * 64 + lane) * 8);

    float bs[4];
#pragma unroll
    for (int g = 0; g < 4; g++) bs[g] = bsum[g * 256 + 16 * w + c16];

    for (int s = ss; s < sse; s++) {
        int pb = (s & 1) * 4096;
        {
            int seq = tid >> 6, cb = (tid & 63) * 2;  // 64 threads/seq, 2 cols each
            const float* xr = x + ((size_t)(sg * 16 + seq) * T_ + s) * C_ + cb;
            float a0 = xr[0], a1 = xr[1], b0 = xr[C_], b1 = xr[C_ + 1];
            f16x2 d2 = {(f16)(b0 - a0), (f16)(b1 - a1)};
            *(f16x2*)(sd + pb + ((seq * 256 + cb * 2) ^ ((seq & 7) << 4))) = d2;
        }
        __syncthreads();
        f32x4 a[4];
#pragma unroll
        for (int g = 0; g < 4; g++) a[g] = (f32x4){0.f, 0.f, 0.f, 0.f};
#pragma unroll
        for (int kf = 0; kf < 4; kf++) {
            f16x8 af = *(const f16x8*)(sd + pb + ((c16 * 256 + (kf * 32 + 8 * quad) * 2) ^ ((c16 & 7) << 4)));
#pragma unroll
            for (int g = 0; g < 4; g++) a[g] = MFMA16(af, wreg[g * 4 + kf], a[g]);
        }
        f16* ob = xp + (((size_t)sg * CHT + (s - cs)) * 16 + w) * 1024 + lane * 4;
#pragma unroll
        for (int g = 0; g < 4; g++) {
            f16x4 o = {(f16)(a[g].x + bs[g]), (f16)(a[g].y + bs[g]),
                       (f16)(a[g].z + bs[g]), (f16)(a[g].w + bs[g])};
            *(f16x4*)(ob + g * 256) = o;
        }
    }
}

// ---------------- K2: recurrence (32 WGs x 1024 thr; 1 WG per 16 seqs per window) ----------------
// 16 waves, 4/SIMD, 128-VGPR budget. Wave w owns j-block 16w, all 4 gates.
// W_hh split: k0..64 LDS image; k64..128 wreg (resident); k192..256 wreg2
// (loop-invariant preheader loads -> compiler keeps resident if regs allow,
// else sinks to in-loop stream = R7 behavior, no worse); k128..192 streamed,
// ALL 8 frags issued at step top, consumed in the last two sections.
// No anti-hoist hack: all addresses are loop-invariant and get hoisted.
__global__ __launch_bounds__(1024)
__attribute__((amdgpu_waves_per_eu(4, 4)))
void k_lstm(const f16* __restrict__ wlds_src, const f16* __restrict__ whhswz,
            const float* __restrict__ bsum, const f16* __restrict__ xp,
            float* __restrict__ feat, char* __restrict__ hstate,
            float* __restrict__ cstate, float* __restrict__ poolstate,
            int cs, int ce, int CHT)
{
    __shared__ __align__(16) char lds[147456];
    const int tid = threadIdx.x, lane = tid & 63, w = tid >> 6;  // w 0..15
    const int wg = blockIdx.x, win = wg >> 4, sg = wg & 15;
    const int c16 = lane & 15, quad = lane >> 4;
    const int a1 = win ? 299 : 154;   // active (nonzero-input) end
    const int t0 = win ? 145 : 0;     // first step
    int s0 = cs > t0 ? cs : t0;
    const int se = ce < 299 ? ce : 299;
    if (s0 >= se) return;
    const bool init = (s0 == t0);

    // stage W k<64 image (swizzled): 1024 threads x 1 col x 128B
    {
        int col = tid;
#pragma unroll
        for (int kb = 0; kb < 8; kb++) {
            f16x8 v = *(const f16x8*)(wlds_src + col * 64 + kb * 8);
            int byte = (col * 128 + kb * 16) ^ ((col & 7) << 4);
            *(f16x8*)(lds + byte) = v;
        }
    }
    // restore / zero the h read-slot for step s0 (parity (s0-1)&1), 8B/thread
    {
        char* slot = lds + HB + (((s0 - 1) & 1) * 8192);
        if (init) {
            f16x4 z = {0, 0, 0, 0};
            *(f16x4*)(slot + tid * 8) = z;
        } else {
            *(f16x4*)(slot + tid * 8) = *(const f16x4*)(hstate + (size_t)wg * 8192 + tid * 8);
        }
    }

    float bs[4];
#pragma unroll
    for (int g = 0; g < 4; g++) bs[g] = bsum[g * 256 + 16 * w + c16];

    f16x8 wreg[8];   // W_hh k64..128 (kfi 0,1)
#pragma unroll
    for (int kfi = 0; kfi < 2; kfi++)
#pragma unroll
        for (int g = 0; g < 4; g++)
            wreg[kfi * 4 + g] = *(const f16x8*)(whhswz + (((size_t)(w * 4 + g) * 6 + kfi) * 64 + lane) * 8);
    f16x8 wreg2[8];  // W_hh k192..256 (kfi 4,5) — loop-invariant, hopefully resident
#pragma unroll
    for (int kfi = 0; kfi < 2; kfi++)
#pragma unroll
        for (int g = 0; g < 4; g++)
            wreg2[kfi * 4 + g] = *(const f16x8*)(whhswz + (((size_t)(w * 4 + g) * 6 + 4 + kfi) * 64 + lane) * 8);

    float cst[4], pool[4];
    if (init) {
#pragma unroll
        for (int i = 0; i < 4; i++) { cst[i] = 0.f; pool[i] = 0.f; }
    } else {
        const float* cp = cstate + ((size_t)wg * 1024 + tid) * 4;
        const float* pp = poolstate + ((size_t)wg * 1024 + tid) * 4;
#pragma unroll
        for (int i = 0; i < 4; i++) { cst[i] = cp[i]; pool[i] = pp[i]; }
    }

    __syncthreads();

    // x_proj fragment pointer (advances 32KB per step)
    const f16* xptr = xp + (((size_t)sg * CHT + (s0 - cs)) * 16 + w) * 1024 + lane * 4;
    f16x4 xc[4];
    if (s0 < a1) {
#pragma unroll
        for (int g = 0; g < 4; g++) xc[g] = *(const f16x4*)(xptr + g * 256);
    }

    // precomputed loop-invariant LDS offsets
    const int aswz = (c16 & 7) << 4;
    const int abase = c16 * 512;
    int afo[8];   // h-read offsets (relative to rb base)
#pragma unroll
    for (int kf = 0; kf < 8; kf++) afo[kf] = (abase + (kf * 32 + 8 * quad) * 2) ^ aswz;
    int bfo[8];   // W image offsets (absolute): [g][kf0/kf1]
#pragma unroll
    for (int g = 0; g < 4; g++) {
        int col = g * 256 + 16 * w + c16;
        int cswz = (col & 7) << 4;
#pragma unroll
        for (int kf = 0; kf < 2; kf++) bfo[g * 2 + kf] = (col * 128 + (kf * 32 + 8 * quad) * 2) ^ cswz;
    }
    int hwo[4];   // h-write offsets (relative to wb base)
#pragma unroll
    for (int r = 0; r < 4; r++) {
        int m = 4 * quad + r;
        int j = 16 * w + c16;
        hwo[r] = (m * 512 + j * 2) ^ ((m & 7) << 4);
    }
    // stream base pointers (kfi 2,3), loop-invariant
    const f16* sp[8];
#pragma unroll
    for (int kfi = 0; kfi < 2; kfi++)
#pragma unroll
        for (int g = 0; g < 4; g++)
            sp[kfi * 4 + g] = whhswz + (((size_t)(w * 4 + g) * 6 + 2 + kfi) * 64 + lane) * 8;

    for (int t = s0; t < se; ++t) {
        // issue ALL streamed weights (k128..192) up front — one L2 round per step
        f16x8 sf[8];
#pragma unroll
        for (int i = 0; i < 8; i++) sf[i] = *(const f16x8*)sp[i];
        // acc init (bias folded into xp)
        f32x4 acc[4];
        if (t < a1) {
#pragma unroll
            for (int g = 0; g < 4; g++)
                acc[g] = (f32x4){(float)xc[g].x, (float)xc[g].y, (float)xc[g].z, (float)xc[g].w};
        } else {
#pragma unroll
            for (int g = 0; g < 4; g++) acc[g] = (f32x4){bs[g], bs[g], bs[g], bs[g]};
        }
        // prefetch next step's x_proj (WAR after acc init)
        xptr += 16384;
        if ((t + 1 < se) && (t + 1 < a1)) {
#pragma unroll
            for (int g = 0; g < 4; g++) xc[g] = *(const f16x4*)(xptr + g * 256);
        }
        const char* rbp = lds + (HB + (((t + 1) & 1)) * 8192);
        char* wbp = lds + (HB + ((t & 1)) * 8192);
        // kf2,kf3 from wreg
#pragma unroll
        for (int k = 0; k < 2; k++) {
            f16x8 af = *(const f16x8*)(rbp + afo[2 + k]);
#pragma unroll
            for (int g = 0; g < 4; g++) acc[g] = MFMA16(af, wreg[k * 4 + g], acc[g]);
        }
        // kf0,kf1 from LDS W image
#pragma unroll
        for (int k = 0; k < 2; k++) {
            f16x8 af = *(const f16x8*)(rbp + afo[k]);
#pragma unroll
            for (int g = 0; g < 4; g++) {
                f16x8 bf = *(const f16x8*)(lds + bfo[g * 2 + k]);
                acc[g] = MFMA16(af, bf, acc[g]);
            }
        }
        // kf6,kf7 from wreg2
#pragma unroll
        for (int k = 0; k < 2; k++) {
            f16x8 af = *(const f16x8*)(rbp + afo[6 + k]);
#pragma unroll
            for (int g = 0; g < 4; g++) acc[g] = MFMA16(af, wreg2[k * 4 + g], acc[g]);
        }
        // kf4,kf5 consume the streamed sf (max latency cover)
#pragma unroll
        for (int k = 0; k < 2; k++) {
            f16x8 af = *(const f16x8*)(rbp + afo[4 + k]);
#pragma unroll
            for (int g = 0; g < 4; g++) acc[g] = MFMA16(af, sf[k * 4 + g], acc[g]);
        }
        // gate math: acc[g][r] = gate g, seq m=4*quad+r, j = 16w + c16
#pragma unroll
        for (int r = 0; r < 4; r++) {
            float gi = acc[0][r], gf = acc[1][r], gg = acc[2][r], go = acc[3][r];
            float c_ = sigm(gf) * cst[r] + sigm(gi) * tanhx(gg);
            cst[r] = c_;
            float h_ = sigm(go) * tanhx(c_);
            pool[r] += h_;
            *(f16*)(wbp + hwo[r]) = (f16)h_;
        }
        __syncthreads();
    }

    if (se < 299) {
        // save state (h slot stable after final barrier)
        const char* slot = lds + HB + (((se - 1) & 1) * 8192);
        *(f16x4*)(hstate + (size_t)wg * 8192 + tid * 8) = *(const f16x4*)(slot + tid * 8);
        float* cp = cstate + ((size_t)wg * 1024 + tid) * 4;
        float* pp = poolstate + ((size_t)wg * 1024 + tid) * 4;
#pragma unroll
        for (int i = 0; i < 4; i++) { cp[i] = cst[i]; pp[i] = pool[i]; }
    } else {
        // pooled hidden -> feat (window-major concat)
#pragma unroll
        for (int r = 0; r < 4; r++) {
            int m = 4 * quad + r;
            int j = 16 * w + c16;
            feat[(size_t)(sg * 16 + m) * 512 + win * 256 + j] = pool[r];
        }
    }
}

// ---------------- K3: final FC ----------------
__global__ void k_fc(const float* __restrict__ feat, const float* __restrict__ Wfc,
                     const float* __restrict__ bfc, float* __restrict__ out)
{
    int b = blockIdx.x, c = threadIdx.x;
    if (c < 60) {
        const float4* fr = (const float4*)(feat + (size_t)b * 512);
        const float4* wr = (const float4*)(Wfc + (size_t)c * 512);
        float s = bfc[c];
        for (int k = 0; k < 128; k++) {
            float4 f = fr[k], ww = wr[k];
            s += f.x * ww.x + f.y * ww.y + f.z * ww.z + f.w * ww.w;
        }
        out[b * 60 + c] = s;
    }
}

extern "C" void kernel_launch(void* const* d_in, const int* in_sizes, int n_in,
                              void* d_out, int out_size, void* d_ws, size_t ws_size,
                              hipStream_t stream)
{
    const float* x   = (const float*)d_in[0];
    const float* Wih = (const float*)d_in[1];
    const float* Whh = (const float*)d_in[2];
    const float* bih = (const float*)d_in[3];
    const float* bhh = (const float*)d_in[4];
    const float* Wfc = (const float*)d_in[5];
    const float* bfc = (const float*)d_in[6];
    float* out = (float*)d_out;

    char* p = (char*)d_ws;
    f16* wlds    = (f16*)p;   p += 131072;            // W_hh k<64 (LDS image)
    f16* whhswz  = (f16*)p;   p += 393216;            // W_hh k64..256 pre-swizzled
    f16* wihswz  = (f16*)p;   p += 262144;            // W_ih pre-swizzled
    float* bsum  = (float*)p; p += 4096;
    float* feat  = (float*)p; p += 524288;            // (256, 512) pooled features
    char* hstate = p;         p += 262144;            // 32 WG x 8KB raw h LDS image
    float* cstate = (float*)p;    p += 524288;
    float* poolstate = (float*)p; p += 524288;
    f16* xp = (f16*)p;
    size_t fixed = (size_t)(p - (char*)d_ws);

    long long avail = (long long)ws_size - (long long)fixed;
    int CHT = (int)(avail / 524288);                  // 512KB of xp per step
    if (CHT < 1) CHT = 1;
    if (CHT > 299) CHT = 299;                         // prefer ONE k_lstm dispatch

    k_prep<<<196, 256, 0, stream>>>(Wih, Whh, bih, bhh, wlds, whhswz, wihswz, bsum);
    for (int cs = 0; cs < 299; cs += CHT) {
        int ce = cs + CHT; if (ce > 299) ce = 299;
        int nb = (ce - cs + 7) / 8;
        k_xproj<<<16 * nb, 1024, 0, stream>>>(x, wihswz, bsum, xp, cs, ce, CHT);
        k_lstm<<<32, 1024, 0, stream>>>(wlds, whhswz, bsum, xp, feat,
                                        hstate, cstate, poolstate, cs, ce, CHT);
    }
    k_fc<<<256, 64, 0, stream>>>(feat, Wfc, bfc, out);
}

// Round 9
// 1354.404 us; speedup vs baseline: 1.9357x; 1.5496x over previous
//
#include <hip/hip_runtime.h>

#define T_ 300
#define C_ 128
#define HB 131072  // byte offset of h double-buffer in k_lstm LDS

typedef _Float16 f16;
typedef _Float16 f16x8 __attribute__((ext_vector_type(8)));
typedef _Float16 f16x4 __attribute__((ext_vector_type(4)));
typedef _Float16 f16x2 __attribute__((ext_vector_type(2)));
typedef float f32x4 __attribute__((ext_vector_type(4)));

#define MFMA16(a, b, c) __builtin_amdgcn_mfma_f32_16x16x32_f16((a), (b), (c), 0, 0, 0)

__device__ __forceinline__ float sigm(float x) {
    return __fdividef(1.f, 1.f + __expf(-x));
}
__device__ __forceinline__ float tanhx(float x) {
    float e = __expf(2.f * x);
    return __builtin_fmaf(-2.f, __frcp_rn(1.f + e), 1.f);
}

// ---------------- K0: weight conversion / pre-swizzle ----------------
__global__ void k_prep(const float* __restrict__ Wih, const float* __restrict__ Whh,
                       const float* __restrict__ bih, const float* __restrict__ bhh,
                       f16* __restrict__ wlds, f16* __restrict__ whhswz,
                       f16* __restrict__ wihswz, float* __restrict__ bsum)
{
    int i = blockIdx.x * 256 + threadIdx.x;
    if (i < 8192) {
        int col = i >> 3, k0 = (i & 7) * 8;
#pragma unroll
        for (int j = 0; j < 8; j++) wlds[col * 64 + k0 + j] = (f16)Whh[col * 256 + k0 + j];
    } else if (i < 32768) {
        // W_hh k64..256 pre-swizzled per (w16, g, kfi 0..5, lane)
        int q = i - 8192; int l = q & 63; q >>= 6;
        int kfi = q % 6; q /= 6;
        int g = q & 3, w16 = q >> 2;
        int col = g * 256 + 16 * w16 + (l & 15);
        int k = 64 + kfi * 32 + 8 * (l >> 4);
        f16* dst = whhswz + (((size_t)(w16 * 4 + g) * 6 + kfi) * 64 + l) * 8;
#pragma unroll
        for (int j = 0; j < 8; j++) dst[j] = (f16)Whh[col * 256 + k + j];
    } else if (i < 49152) {
        // W_ih k0..128 pre-swizzled per (w16, g, kfi 0..3, lane)
        int q = i - 32768; int l = q & 63; q >>= 6;
        int kfi = q & 3; q >>= 2;
        int g = q & 3, w16 = q >> 2;
        int col = g * 256 + 16 * w16 + (l & 15);
        int k = kfi * 32 + 8 * (l >> 4);
        f16* dst = wihswz + (((size_t)(w16 * 4 + g) * 4 + kfi) * 64 + l) * 8;
#pragma unroll
        for (int j = 0; j < 8; j++) dst[j] = (f16)Wih[col * 128 + k + j];
    } else if (i < 50176) {
        int j = i - 49152;
        bsum[j] = bih[j] + bhh[j];
    }
}

// ---------------- K1: x_proj precompute (fully parallel) ----------------
__global__ __launch_bounds__(1024)
__attribute__((amdgpu_waves_per_eu(4, 4)))
void k_xproj(const float* __restrict__ x, const f16* __restrict__ wihswz,
             const float* __restrict__ bsum, f16* __restrict__ xp,
             int cs, int ce, int CHT)
{
    __shared__ __align__(16) char sd[8192];
    const int tid = threadIdx.x, lane = tid & 63, w = tid >> 6;
    const int sg = blockIdx.x & 15, tb = blockIdx.x >> 4;
    const int c16 = lane & 15, quad = lane >> 4;
    int ss = cs + tb * 8;
    int sse = ss + 8; if (sse > ce) sse = ce;

    f16x8 wreg[16];
#pragma unroll
    for (int g = 0; g < 4; g++)
#pragma unroll
        for (int kfi = 0; kfi < 4; kfi++)
            wreg[g * 4 + kfi] = *(const f16x8*)(wihswz + (((size_t)(w * 4 + g) * 4 + kfi) * 64 + lane) * 8);

    float bs[4];
#pragma unroll
    for (int g = 0; g < 4; g++) bs[g] = bsum[g * 256 + 16 * w + c16];

    for (int s = ss; s < sse; s++) {
        int pb = (s & 1) * 4096;
        {
            int seq = tid >> 6, cb = (tid & 63) * 2;
            const float* xr = x + ((size_t)(sg * 16 + seq) * T_ + s) * C_ + cb;
            float a0 = xr[0], a1 = xr[1], b0 = xr[C_], b1 = xr[C_ + 1];
            f16x2 d2 = {(f16)(b0 - a0), (f16)(b1 - a1)};
            *(f16x2*)(sd + pb + ((seq * 256 + cb * 2) ^ ((seq & 7) << 4))) = d2;
        }
        __syncthreads();
        f32x4 a[4];
#pragma unroll
        for (int g = 0; g < 4; g++) a[g] = (f32x4){0.f, 0.f, 0.f, 0.f};
#pragma unroll
        for (int kf = 0; kf < 4; kf++) {
            f16x8 af = *(const f16x8*)(sd + pb + ((c16 * 256 + (kf * 32 + 8 * quad) * 2) ^ ((c16 & 7) << 4)));
#pragma unroll
            for (int g = 0; g < 4; g++) a[g] = MFMA16(af, wreg[g * 4 + kf], a[g]);
        }
        f16* ob = xp + (((size_t)sg * CHT + (s - cs)) * 16 + w) * 1024 + lane * 4;
#pragma unroll
        for (int g = 0; g < 4; g++) {
            f16x4 o = {(f16)(a[g].x + bs[g]), (f16)(a[g].y + bs[g]),
                       (f16)(a[g].z + bs[g]), (f16)(a[g].w + bs[g])};
            *(f16x4*)(ob + g * 256) = o;
        }
    }
}

// ---------------- K2: recurrence — explicit asm-pipelined streaming ----------------
// 32 WGs x 1024 thr; wave w owns j-block 16w, all 4 gates. K split:
//   k0..64   : LDS W image (2 sections)
//   k64..256 : 6 streamed rounds (kfi0..5) via asm global_load into X/Y/Z
//              ping-pong buffers, issued >=3 sections (or a whole step) ahead,
//              consumed behind hand-counted s_waitcnt vmcnt(N).
// No vmcnt(0) in the loop: raw "lgkmcnt(0); s_barrier" keeps 12 loads in
// flight across every step barrier. All stream loads are idempotent (same
// address each step) so buffer over-issue is benign.
#define VMW(N)  asm volatile("s_waitcnt vmcnt(" #N ")"); __builtin_amdgcn_sched_barrier(0x186);
#define VMW0(N) asm volatile("s_waitcnt vmcnt(" #N ")"); __builtin_amdgcn_sched_barrier(0);
#define GL(dst, voff, IMM) asm volatile("global_load_dwordx4 %0, %1, %2 offset:" IMM : "=v"(dst) : "v"(voff), "s"(wsz))
#define GLX(dst, IMM)      asm volatile("global_load_dwordx2 %0, %1, off offset:" IMM : "=v"(dst) : "v"(xaddr))
#define ISS_K0() GL(X0,voffA0,"0");    GL(X1,voffA1,"0");    GL(X2,voffA2,"0");    GL(X3,voffA3,"0")
#define ISS_K1() GL(Y0,voffA0,"1024"); GL(Y1,voffA1,"1024"); GL(Y2,voffA2,"1024"); GL(Y3,voffA3,"1024")
#define ISS_K2() GL(Z0,voffA0,"2048"); GL(Z1,voffA1,"2048"); GL(Z2,voffA2,"2048"); GL(Z3,voffA3,"2048")
#define ISS_K3() GL(X0,voffB0,"0");    GL(X1,voffB1,"0");    GL(X2,voffB2,"0");    GL(X3,voffB3,"0")
#define ISS_K4() GL(Y0,voffB0,"1024"); GL(Y1,voffB1,"1024"); GL(Y2,voffB2,"1024"); GL(Y3,voffB3,"1024")
#define ISS_K5() GL(Z0,voffB0,"2048"); GL(Z1,voffB1,"2048"); GL(Z2,voffB2,"2048"); GL(Z3,voffB3,"2048")
#define ISS_XC() GLX(xv0,"0"); GLX(xv1,"512"); GLX(xv2,"1024"); GLX(xv3,"1536")
#define SEC(AFO, B0,B1,B2,B3) { f16x8 af = *(const f16x8*)(rbp + AFO); \
    acc0 = MFMA16(af, B0, acc0); acc1 = MFMA16(af, B1, acc1); \
    acc2 = MFMA16(af, B2, acc2); acc3 = MFMA16(af, B3, acc3); }
#define SECIMG(AFO, O0,O1,O2,O3) { f16x8 af = *(const f16x8*)(rbp + AFO); \
    { f16x8 b = *(const f16x8*)(lds + O0); acc0 = MFMA16(af, b, acc0); } \
    { f16x8 b = *(const f16x8*)(lds + O1); acc1 = MFMA16(af, b, acc1); } \
    { f16x8 b = *(const f16x8*)(lds + O2); acc2 = MFMA16(af, b, acc2); } \
    { f16x8 b = *(const f16x8*)(lds + O3); acc3 = MFMA16(af, b, acc3); } }
#define GATES_AND_BARRIER() \
        { \
            _Pragma("unroll") \
            for (int r = 0; r < 4; r++) { \
                float gi = acc0[r], gf = acc1[r], gg = acc2[r], go = acc3[r]; \
                float c_ = sigm(gf) * cst[r] + sigm(gi) * tanhx(gg); \
                cst[r] = c_; \
                float h_ = sigm(go) * tanhx(c_); \
                pool[r] += h_; \
                *(f16*)(wbp + hwo[r]) = (f16)h_; \
            } \
        } \
        asm volatile("s_waitcnt lgkmcnt(0)\n\ts_barrier" ::: "memory");

__global__ __launch_bounds__(1024)
__attribute__((amdgpu_waves_per_eu(4, 4)))
void k_lstm(const f16* __restrict__ wlds_src, const f16* __restrict__ whhswz,
            const float* __restrict__ bsum, const f16* __restrict__ xp,
            float* __restrict__ feat, char* __restrict__ hstate,
            float* __restrict__ cstate, float* __restrict__ poolstate,
            int cs, int ce, int CHT)
{
    __shared__ __align__(16) char lds[147456];
    const int tid = threadIdx.x, lane = tid & 63, w = tid >> 6;
    const int wg = blockIdx.x, win = wg >> 4, sg = wg & 15;
    const int c16 = lane & 15, quad = lane >> 4;
    const int a1 = win ? 299 : 154;
    const int t0 = win ? 145 : 0;
    int s0 = cs > t0 ? cs : t0;
    const int se = ce < 299 ? ce : 299;
    if (s0 >= se) return;
    const bool init = (s0 == t0);
    const f16* wsz = whhswz;

    // stage W k<64 image (swizzled)
    {
        int col = tid;
#pragma unroll
        for (int kb = 0; kb < 8; kb++) {
            f16x8 v = *(const f16x8*)(wlds_src + col * 64 + kb * 8);
            int byte = (col * 128 + kb * 16) ^ ((col & 7) << 4);
            *(f16x8*)(lds + byte) = v;
        }
    }
    // restore / zero h read-slot for step s0
    {
        char* slot = lds + HB + (((s0 - 1) & 1) * 8192);
        if (init) {
            f16x4 z = {0, 0, 0, 0};
            *(f16x4*)(slot + tid * 8) = z;
        } else {
            *(f16x4*)(slot + tid * 8) = *(const f16x4*)(hstate + (size_t)wg * 8192 + tid * 8);
        }
    }

    float bs0 = bsum[0 * 256 + 16 * w + c16];
    float bs1 = bsum[1 * 256 + 16 * w + c16];
    float bs2 = bsum[2 * 256 + 16 * w + c16];
    float bs3 = bsum[3 * 256 + 16 * w + c16];

    float cst[4], pool[4];
    if (init) {
#pragma unroll
        for (int i = 0; i < 4; i++) { cst[i] = 0.f; pool[i] = 0.f; }
    } else {
        const float* cp = cstate + ((size_t)wg * 1024 + tid) * 4;
        const float* pp = poolstate + ((size_t)wg * 1024 + tid) * 4;
#pragma unroll
        for (int i = 0; i < 4; i++) { cst[i] = cp[i]; pool[i] = pp[i]; }
    }

    // loop-invariant offsets
    const int aswz = (c16 & 7) << 4;
    const int abase = c16 * 512;
    int afo[8];
#pragma unroll
    for (int kf = 0; kf < 8; kf++) afo[kf] = (abase + (kf * 32 + 8 * quad) * 2) ^ aswz;
    int bfo[8];
#pragma unroll
    for (int g = 0; g < 4; g++) {
        int col = g * 256 + 16 * w + c16;
        int cswz = (col & 7) << 4;
#pragma unroll
        for (int kf = 0; kf < 2; kf++) bfo[g * 2 + kf] = (col * 128 + (kf * 32 + 8 * quad) * 2) ^ cswz;
    }
    int hwo[4];
#pragma unroll
    for (int r = 0; r < 4; r++) {
        int m = 4 * quad + r;
        hwo[r] = (m * 512 + (16 * w + c16) * 2) ^ ((m & 7) << 4);
    }
    // stream voffsets: byte = (w*4+g)*6144 + kfi*1024 + lane*16
    unsigned voffA0 = (unsigned)((w * 4 + 0) * 6144 + lane * 16);
    unsigned voffA1 = (unsigned)((w * 4 + 1) * 6144 + lane * 16);
    unsigned voffA2 = (unsigned)((w * 4 + 2) * 6144 + lane * 16);
    unsigned voffA3 = (unsigned)((w * 4 + 3) * 6144 + lane * 16);
    unsigned voffB0 = voffA0 + 3072, voffB1 = voffA1 + 3072;
    unsigned voffB2 = voffA2 + 3072, voffB3 = voffA3 + 3072;
    unsigned long long xaddr = (unsigned long long)xp
        + (((unsigned long long)sg * CHT + (unsigned)(s0 - cs)) * 16 + (unsigned)w) * 2048ull
        + (unsigned)lane * 8ull;

    f16x8 X0, X1, X2, X3, Y0, Y1, Y2, Y3, Z0, Z1, Z2, Z3;
    f16x4 xv0, xv1, xv2, xv3;

    __syncthreads();

    const int ae = se < a1 ? se : a1;   // active end
    if (s0 < a1) { ISS_XC(); ISS_K0(); ISS_K1(); ISS_K2(); }

    // ---------------- ACTIVE phase ----------------
    for (int t = s0; t < ae; ++t) {
        const char* rbp = lds + HB + (((t + 1) & 1) << 13);
        char* wbp = lds + HB + ((t & 1) << 13);
        VMW0(12);   // drain xc for this step
        f32x4 acc0 = {(float)xv0.x, (float)xv0.y, (float)xv0.z, (float)xv0.w};
        f32x4 acc1 = {(float)xv1.x, (float)xv1.y, (float)xv1.z, (float)xv1.w};
        f32x4 acc2 = {(float)xv2.x, (float)xv2.y, (float)xv2.z, (float)xv2.w};
        f32x4 acc3 = {(float)xv3.x, (float)xv3.y, (float)xv3.z, (float)xv3.w};
        xaddr += 32768ull;
        ISS_XC();                         // t+1, in flight across barrier
        SECIMG(afo[0], bfo[0], bfo[2], bfo[4], bfo[6]);   // k0..32
        SECIMG(afo[1], bfo[1], bfo[3], bfo[5], bfo[7]);   // k32..64
        VMW(12); SEC(afo[2], X0, X1, X2, X3); ISS_K3();   // k64..96
        VMW(12); SEC(afo[3], Y0, Y1, Y2, Y3); ISS_K4();   // k96..128
        VMW(12); SEC(afo[4], Z0, Z1, Z2, Z3); ISS_K5();   // k128..160
        VMW(8);  SEC(afo[5], X0, X1, X2, X3); ISS_K0();   // k160..192
        VMW(8);  SEC(afo[6], Y0, Y1, Y2, Y3); ISS_K1();   // k192..224
        VMW(8);  SEC(afo[7], Z0, Z1, Z2, Z3); ISS_K2();   // k224..256
        GATES_AND_BARRIER();
    }

    // ---------------- IDLE phase (win0 tail: zero input) ----------------
    const int is0 = s0 > a1 ? s0 : a1;
    if (is0 < se && s0 >= a1) { ISS_K0(); ISS_K1(); ISS_K2(); }
    for (int t = is0; t < se; ++t) {
        const char* rbp = lds + HB + (((t + 1) & 1) << 13);
        char* wbp = lds + HB + ((t & 1) << 13);
        f32x4 acc0 = {bs0, bs0, bs0, bs0};
        f32x4 acc1 = {bs1, bs1, bs1, bs1};
        f32x4 acc2 = {bs2, bs2, bs2, bs2};
        f32x4 acc3 = {bs3, bs3, bs3, bs3};
        SECIMG(afo[0], bfo[0], bfo[2], bfo[4], bfo[6]);
        SECIMG(afo[1], bfo[1], bfo[3], bfo[5], bfo[7]);
        VMW(8); SEC(afo[2], X0, X1, X2, X3); ISS_K3();
        VMW(8); SEC(afo[3], Y0, Y1, Y2, Y3); ISS_K4();
        VMW(8); SEC(afo[4], Z0, Z1, Z2, Z3); ISS_K5();
        VMW(8); SEC(afo[5], X0, X1, X2, X3); ISS_K0();
        VMW(8); SEC(afo[6], Y0, Y1, Y2, Y3); ISS_K1();
        VMW(8); SEC(afo[7], Z0, Z1, Z2, Z3); ISS_K2();
        GATES_AND_BARRIER();
    }

    if (se < 299) {
        const char* slot = lds + HB + (((se - 1) & 1) * 8192);
        *(f16x4*)(hstate + (size_t)wg * 8192 + tid * 8) = *(const f16x4*)(slot + tid * 8);
        float* cp = cstate + ((size_t)wg * 1024 + tid) * 4;
        float* pp = poolstate + ((size_t)wg * 1024 + tid) * 4;
#pragma unroll
        for (int i = 0; i < 4; i++) { cp[i] = cst[i]; pp[i] = pool[i]; }
    } else {
#pragma unroll
        for (int r = 0; r < 4; r++) {
            int m = 4 * quad + r;
            feat[(size_t)(sg * 16 + m) * 512 + win * 256 + 16 * w + c16] = pool[r];
        }
    }
}

// ---------------- K3: final FC ----------------
__global__ void k_fc(const float* __restrict__ feat, const float* __restrict__ Wfc,
                     const float* __restrict__ bfc, float* __restrict__ out)
{
    int b = blockIdx.x, c = threadIdx.x;
    if (c < 60) {
        const float4* fr = (const float4*)(feat + (size_t)b * 512);
        const float4* wr = (const float4*)(Wfc + (size_t)c * 512);
        float s = bfc[c];
        for (int k = 0; k < 128; k++) {
            float4 f = fr[k], ww = wr[k];
            s += f.x * ww.x + f.y * ww.y + f.z * ww.z + f.w * ww.w;
        }
        out[b * 60 + c] = s;
    }
}

extern "C" void kernel_launch(void* const* d_in, const int* in_sizes, int n_in,
                              void* d_out, int out_size, void* d_ws, size_t ws_size,
                              hipStream_t stream)
{
    const float* x   = (const float*)d_in[0];
    const float* Wih = (const float*)d_in[1];
    const float* Whh = (const float*)d_in[2];
    const float* bih = (const float*)d_in[3];
    const float* bhh = (const float*)d_in[4];
    const float* Wfc = (const float*)d_in[5];
    const float* bfc = (const float*)d_in[6];
    float* out = (float*)d_out;

    char* p = (char*)d_ws;
    f16* wlds    = (f16*)p;   p += 131072;
    f16* whhswz  = (f16*)p;   p += 393216;
    f16* wihswz  = (f16*)p;   p += 262144;
    float* bsum  = (float*)p; p += 4096;
    float* feat  = (float*)p; p += 524288;
    char* hstate = p;         p += 262144;
    float* cstate = (float*)p;    p += 524288;
    float* poolstate = (float*)p; p += 524288;
    f16* xp = (f16*)p;
    size_t fixed = (size_t)(p - (char*)d_ws);

    long long avail = (long long)ws_size - (long long)fixed;
    int CHT = (int)(avail / 524288);
    if (CHT < 1) CHT = 1;
    if (CHT > 299) CHT = 299;

    k_prep<<<196, 256, 0, stream>>>(Wih, Whh, bih, bhh, wlds, whhswz, wihswz, bsum);
    for (int cs = 0; cs < 299; cs += CHT) {
        int ce = cs + CHT; if (ce > 299) ce = 299;
        int nb = (ce - cs + 7) / 8;
        k_xproj<<<16 * nb, 1024, 0, stream>>>(x, wihswz, bsum, xp, cs, ce, CHT);
        k_lstm<<<32, 1024, 0, stream>>>(wlds, whhswz, bsum, xp, feat,
                                        hstate, cstate, poolstate, cs, ce, CHT);
    }
    k_fc<<<256, 64, 0, stream>>>(feat, Wfc, bfc, out);
}